// Round 2
// baseline (381.016 us; speedup 1.0000x reference)
//
#include <hip/hip_runtime.h>
#include <stdint.h>
#include <stddef.h>

// Problem constants
#define N_B   32
#define C_CH  256
#define H_S   56
#define W_S   56
#define HW    (H_S*W_S)        // 3136
#define NSP   (N_B*HW)         // 100352
#define KTOT  (C_CH*9)         // 2304 (bytes per row in i8)
#define HP    58               // padded spatial
#define NK    36               // KTOT/64

// Workspace layout (bytes) — all i8
#define XPAD_BYTES ((size_t)N_B*HP*HP*C_CH)        // 27,557,888
#define WB_OFF_B   XPAD_BYTES
#define WB_BYTES   ((size_t)C_CH*KTOT)             // 589,824
#define Y_OFF_B    (WB_OFF_B + WB_BYTES)
#define STAT_OFF_B (Y_OFF_B + (size_t)C_CH*NSP*2)

typedef int    int4v  __attribute__((ext_vector_type(4)));
typedef short  s16x4  __attribute__((ext_vector_type(4)));
typedef char   char8  __attribute__((ext_vector_type(8)));
typedef float  f32x4v __attribute__((ext_vector_type(4)));

__device__ __forceinline__ void gl16(const void* g, void* l) {
    __builtin_amdgcn_global_load_lds((const __attribute__((address_space(1))) void*)g,
                                     (__attribute__((address_space(3))) void*)l, 16, 0, 0);
}

__device__ __forceinline__ char sign_i8(float v) {
    return v > 0.f ? (char)1 : (v < 0.f ? (char)-1 : (char)0);
}

// --- binarize weights (i8), reorder K; also zero the stat accumulators
__global__ __launch_bounds__(256) void k_binw(const float* __restrict__ w,
                                              char* __restrict__ wb,
                                              float* __restrict__ gStat) {
    int g = blockIdx.x * 256 + threadIdx.x;
    if (blockIdx.x == 0 && threadIdx.x < 512) gStat[threadIdx.x] = 0.f;
    if (g >= (int)WB_BYTES) return;
    int co = g / KTOT;
    int r  = g - co * KTOT;
    int ci = r / 9;
    int koff = r - ci * 9;
    wb[co * KTOT + koff * C_CH + ci] = sign_i8(w[g]);
}

// --- binarize x into zero-padded [nb][h+1][w+1][ci] i8 via LDS transpose
__global__ __launch_bounds__(256) void k_binx(const float* __restrict__ x,
                                              char* __restrict__ xpad) {
    __shared__ short tile[32 * 66];   // [ci_l][hw], stride 66 kills bank conflicts
    const int t   = threadIdx.x;
    const int hw0 = blockIdx.x * 64;
    const int ci0 = blockIdx.y * 32;
    const int nb  = blockIdx.z;
    const int lhw = t & 63;
    const int cq  = t >> 6;    // 0..3
#pragma unroll
    for (int p = 0; p < 8; ++p) {
        int ci_l = cq + p * 4;
        float v = x[((size_t)(nb * C_CH + ci0 + ci_l)) * HW + hw0 + lhw];
        tile[ci_l * 66 + lhw] = (short)sign_i8(v);
    }
    __syncthreads();
    const int hwi = t >> 2;    // 0..63
    const int ch  = t & 3;     // 8 ci each
    const int hw  = hw0 + hwi;
    const int h   = hw / 56, w_ = hw - h * 56;
    char8 pk;
#pragma unroll
    for (int i = 0; i < 8; ++i) pk[i] = (char)tile[(ch * 8 + i) * 66 + hwi];
    size_t dst = ((size_t)((nb * HP + h + 1) * HP + (w_ + 1))) * C_CH + ci0 + ch * 8;
    *(char8*)(xpad + dst) = pk;   // 8B aligned contiguous
}

// --- implicit-GEMM conv (i8 MFMA): y[co][nsp]; fused channel sum/sumsq
// Round-2 changes:
//   * A (binarized weights, 576KB, L2-resident) no longer staged in LDS:
//     loaded straight into registers (compiler-tracked dwordx4, double-
//     buffered via unroll named regs). Halves LDS traffic (48->24KB/blk-iter),
//     LDS 33.8->25.6KB.
//   * T4 counted vmcnt: per K-step, stage next tile (2 gl16 + 4 A-loads = 6
//     VMEM), then `s_waitcnt vmcnt(6)` (current tile's 6 are done, next 6
//     stay in flight), raw s_barrier, sched_barrier(0) fence (rule #18).
//     NO vmcnt(0) drain anywhere in the main loop.
//   * 3-deep B LDS rotation -> a single barrier per K-step is race-free:
//     buffer (kb+1)%3 was last *read* at step kb-2, i.e. two barriers ago;
//     ds_read completion is forced by the MFMA lgkmcnt data-dep before the
//     intervening barrier.
__global__ __launch_bounds__(256) void k_conv(const char* __restrict__ xpad,
                                              const char* __restrict__ wb,
                                              short* __restrict__ y16,
                                              float* __restrict__ gSum,
                                              float* __restrict__ gSqs) {
    __shared__ char lB[3][8192];     // [buf][n_row 0..127][k 0..63] (swizzled chunks)
    __shared__ float sSum[128], sSqs[128];

    const int t    = threadIdx.x;
    const int wave = t >> 6, lane = t & 63;
    const int quad = lane >> 4, l16 = lane & 15;
    const int wm   = wave & 1, wn = wave >> 1;
    const int n0   = blockIdx.x * 128;
    const int co0  = blockIdx.y * 128;

    if (t < 128) { sSum[t] = 0.f; sSqs[t] = 0.f; }

    // B staging addresses (lane -> 16 rows x 4 chunks of 16B), T2 pre-swizzled source
    const int lr  = lane >> 2;              // row within 16-row chunk
    const int lc  = lane & 3;               // 16B chunk within 64B row
    const int lcs = lc ^ ((lr >> 1) & 3);   // pre-swizzled source chunk
    int nsp0 = n0 + wave * 32 + lr;
    int nb0 = nsp0 / HW; int hwr0 = nsp0 - nb0 * HW; int h0 = hwr0 / 56; int w0 = hwr0 - h0 * 56;
    const uint32_t bOff0 = (uint32_t)((nb0 * HP + h0) * HP + w0) * C_CH + lcs * 16;
    int nsp1 = nsp0 + 16;
    int nb1 = nsp1 / HW; int hwr1 = nsp1 - nb1 * HW; int h1 = hwr1 / 56; int w1 = hwr1 - h1 * 56;
    const uint32_t bOff1 = (uint32_t)((nb1 * HP + h1) * HP + w1) * C_CH + lcs * 16;

    // read-side swizzled chunk offset (constant per lane)
    const int rds = (quad ^ ((l16 >> 1) & 3)) * 16;

    // A direct-from-global fragment base: row = co0 + wm*64 + mi*16 + l16,
    // bytes [kb*64 + quad*16, +16)
    const char* aBase = wb + (uint32_t)(co0 + wm * 64 + l16) * KTOT + quad * 16;

    int4v acc[4][4];
#pragma unroll
    for (int i = 0; i < 4; ++i)
#pragma unroll
        for (int j = 0; j < 4; ++j) acc[i][j] = (int4v){0, 0, 0, 0};

    int4v aX0, aX1, aX2, aX3, aY0, aY1, aY2, aY3;

#define STAGE_B(kb_, SB) do {                                               \
        const int koff_ = (kb_) >> 2;               /* (kh,kw) index 0..8 */\
        const int ci0_  = ((kb_) & 3) * 64;                                 \
        const int kh_   = koff_ / 3;                                        \
        const int kw_   = koff_ - kh_ * 3;                                  \
        const uint32_t bAdd_ = (uint32_t)(kh_ * HP + kw_) * C_CH + ci0_;    \
        gl16(xpad + bOff0 + bAdd_, &lB[SB][wave * 2048]);                   \
        gl16(xpad + bOff1 + bAdd_, &lB[SB][wave * 2048 + 1024]);            \
    } while (0)

#define LOADA(kb_, A0, A1, A2, A3) do {                                     \
        const char* ap_ = aBase + (uint32_t)(kb_) * 64;                     \
        A0 = *(const int4v*)(ap_);                                          \
        A1 = *(const int4v*)(ap_ + 16 * KTOT);                              \
        A2 = *(const int4v*)(ap_ + 32 * KTOT);                              \
        A3 = *(const int4v*)(ap_ + 48 * KTOT);                              \
    } while (0)

#define MFROW(AR, r_)                                                              \
        acc[r_][0] = __builtin_amdgcn_mfma_i32_16x16x64_i8(AR, bf0, acc[r_][0], 0, 0, 0); \
        acc[r_][1] = __builtin_amdgcn_mfma_i32_16x16x64_i8(AR, bf1, acc[r_][1], 0, 0, 0); \
        acc[r_][2] = __builtin_amdgcn_mfma_i32_16x16x64_i8(AR, bf2, acc[r_][2], 0, 0, 0); \
        acc[r_][3] = __builtin_amdgcn_mfma_i32_16x16x64_i8(AR, bf3, acc[r_][3], 0, 0, 0);

#define COMPUTE(RB, A0, A1, A2, A3) do {                                    \
        int4v bf0 = *(const int4v*)&lB[RB][(wn * 64 +  0 + l16) * 64 + rds];\
        int4v bf1 = *(const int4v*)&lB[RB][(wn * 64 + 16 + l16) * 64 + rds];\
        int4v bf2 = *(const int4v*)&lB[RB][(wn * 64 + 32 + l16) * 64 + rds];\
        int4v bf3 = *(const int4v*)&lB[RB][(wn * 64 + 48 + l16) * 64 + rds];\
        __builtin_amdgcn_s_setprio(1);                                      \
        MFROW(A0, 0)                                                        \
        MFROW(A1, 1)                                                        \
        MFROW(A2, 2)                                                        \
        MFROW(A3, 3)                                                        \
        __builtin_amdgcn_s_setprio(0);                                      \
    } while (0)

#define SUB(kb_, RB, SB, AC0, AC1, AC2, AC3, AN0, AN1, AN2, AN3) do {       \
        if ((kb_) + 1 < NK) {                                               \
            STAGE_B((kb_) + 1, SB);                                         \
            LOADA((kb_) + 1, AN0, AN1, AN2, AN3);                           \
            asm volatile("s_waitcnt vmcnt(6)" ::: "memory");                \
        } else {                                                            \
            asm volatile("s_waitcnt vmcnt(0)" ::: "memory");                \
        }                                                                   \
        __builtin_amdgcn_s_barrier();                                       \
        __builtin_amdgcn_sched_barrier(0);                                  \
        COMPUTE(RB, AC0, AC1, AC2, AC3);                                    \
    } while (0)

    STAGE_B(0, 0);
    LOADA(0, aX0, aX1, aX2, aX3);

    for (int kbb = 0; kbb < NK; kbb += 6) {
        SUB(kbb + 0, 0, 1, aX0, aX1, aX2, aX3, aY0, aY1, aY2, aY3);
        SUB(kbb + 1, 1, 2, aY0, aY1, aY2, aY3, aX0, aX1, aX2, aX3);
        SUB(kbb + 2, 2, 0, aX0, aX1, aX2, aX3, aY0, aY1, aY2, aY3);
        SUB(kbb + 3, 0, 1, aY0, aY1, aY2, aY3, aX0, aX1, aX2, aX3);
        SUB(kbb + 4, 1, 2, aX0, aX1, aX2, aX3, aY0, aY1, aY2, aY3);
        SUB(kbb + 5, 2, 0, aY0, aY1, aY2, aY3, aX0, aX1, aX2, aX3);
    }
#undef SUB
#undef COMPUTE
#undef MFROW
#undef LOADA
#undef STAGE_B

    // epilogue: y16 store + per-channel partial sums
#pragma unroll
    for (int mi = 0; mi < 4; ++mi) {
#pragma unroll
        for (int r = 0; r < 4; ++r) {
            int m = co0 + wm * 64 + mi * 16 + quad * 4 + r;
            float s = 0.f, sq = 0.f;
#pragma unroll
            for (int ni = 0; ni < 4; ++ni) {
                int yi = acc[mi][ni][r];      // exact integer
                float f = (float)yi;
                int n = n0 + wn * 64 + ni * 16 + l16;
                y16[(uint32_t)m * NSP + n] = (short)yi;
                s += f; sq += f * f;
            }
#pragma unroll
            for (int off = 1; off < 16; off <<= 1) {
                s  += __shfl_xor(s, off);
                sq += __shfl_xor(sq, off);
            }
            if (l16 == 0) {
                atomicAdd(&sSum[m - co0], s);
                atomicAdd(&sSqs[m - co0], sq);
            }
        }
    }
    __syncthreads();
    if (t < 128) {
        atomicAdd(&gSum[co0 + t], sSum[t]);
        atomicAdd(&gSqs[co0 + t], sSqs[t]);
    }
}

// --- fused BN stats + apply + residual
__global__ __launch_bounds__(256) void k_out(const short* __restrict__ y16,
                                             const float* __restrict__ x,
                                             const float* __restrict__ gSum,
                                             const float* __restrict__ gSqs,
                                             const float* __restrict__ gamma,
                                             const float* __restrict__ beta,
                                             float* __restrict__ out) {
    int g = blockIdx.x * 256 + threadIdx.x;       // NSP*C_CH/4 threads
    int hw4 = g % 784;
    int tmp = g / 784;
    int co  = tmp & 255;
    int nb  = tmp >> 8;
    const float inv = 1.0f / (float)NSP;
    float mean = gSum[co] * inv;
    float var  = gSqs[co] * inv - mean * mean;
    float a = gamma[co] * rsqrtf(var + 1e-5f);
    float b = beta[co] - mean * a;
    s16x4 yv = *(const s16x4*)&y16[(uint32_t)co * NSP + nb * HW + hw4 * 4];
    size_t xi = ((size_t)(nb * C_CH + co)) * HW + hw4 * 4;
    f32x4v xv = *(const f32x4v*)&x[xi];
    f32x4v o;
#pragma unroll
    for (int i = 0; i < 4; ++i) o[i] = a * (float)yv[i] + b + xv[i];
    *(f32x4v*)&out[xi] = o;
}

extern "C" void kernel_launch(void* const* d_in, const int* in_sizes, int n_in,
                              void* d_out, int out_size, void* d_ws, size_t ws_size,
                              hipStream_t stream) {
    const float* x     = (const float*)d_in[0];
    const float* w     = (const float*)d_in[1];
    const float* gamma = (const float*)d_in[2];
    const float* beta  = (const float*)d_in[3];
    float* out = (float*)d_out;
    char* ws = (char*)d_ws;

    char*  xpad = ws;
    char*  wbp  = ws + WB_OFF_B;
    short* y16  = (short*)(ws + Y_OFF_B);
    float* gSum = (float*)(ws + STAT_OFF_B);
    float* gSqs = gSum + 256;

    hipMemsetAsync(xpad, 0, XPAD_BYTES, stream);                 // padding zeros

    k_binw<<<(int)((WB_BYTES + 255) / 256), 256, 0, stream>>>(w, wbp, gSum);
    k_binx<<<dim3(49, 8, 32), 256, 0, stream>>>(x, xpad);
    k_conv<<<dim3(NSP / 128, 2), 256, 0, stream>>>(xpad, wbp, y16, gSum, gSqs);
    k_out<<<(NSP * C_CH / 4) / 256, 256, 0, stream>>>(y16, x, gSum, gSqs, gamma, beta, out);
}

// Round 3
// 346.138 us; speedup vs baseline: 1.1008x; 1.1008x over previous
//
#include <hip/hip_runtime.h>
#include <stdint.h>
#include <stddef.h>

// Problem constants
#define N_B   32
#define C_CH  256
#define H_S   56
#define W_S   56
#define HW    (H_S*W_S)        // 3136
#define NSP   (N_B*HW)         // 100352
#define KTOT  (C_CH*9)         // 2304 (bytes per row in i8)
#define HP    58               // padded spatial
#define NK    36               // KTOT/64

// Workspace layout (bytes) — all i8
#define XPAD_BYTES ((size_t)N_B*HP*HP*C_CH)        // 27,557,888
#define WB_OFF_B   XPAD_BYTES
#define WB_BYTES   ((size_t)C_CH*KTOT)             // 589,824
#define Y_OFF_B    (WB_OFF_B + WB_BYTES)
#define STAT_OFF_B (Y_OFF_B + (size_t)C_CH*NSP*2)

typedef int    int4v  __attribute__((ext_vector_type(4)));
typedef short  s16x4  __attribute__((ext_vector_type(4)));
typedef char   char8  __attribute__((ext_vector_type(8)));
typedef float  f32x4v __attribute__((ext_vector_type(4)));

__device__ __forceinline__ void gl16(const void* g, void* l) {
    __builtin_amdgcn_global_load_lds((const __attribute__((address_space(1))) void*)g,
                                     (__attribute__((address_space(3))) void*)l, 16, 0, 0);
}

__device__ __forceinline__ char sign_i8(float v) {
    return v > 0.f ? (char)1 : (v < 0.f ? (char)-1 : (char)0);
}

// --- binarize weights (i8), reorder K; also zero the stat accumulators
__global__ __launch_bounds__(256) void k_binw(const float* __restrict__ w,
                                              char* __restrict__ wb,
                                              float* __restrict__ gStat) {
    int g = blockIdx.x * 256 + threadIdx.x;
    if (blockIdx.x == 0 && threadIdx.x < 512) gStat[threadIdx.x] = 0.f;
    if (g >= (int)WB_BYTES) return;
    int co = g / KTOT;
    int r  = g - co * KTOT;
    int ci = r / 9;
    int koff = r - ci * 9;
    wb[co * KTOT + koff * C_CH + ci] = sign_i8(w[g]);
}

// --- binarize x into zero-padded [nb][h+1][w+1][ci] i8 via LDS transpose
__global__ __launch_bounds__(256) void k_binx(const float* __restrict__ x,
                                              char* __restrict__ xpad) {
    __shared__ short tile[32 * 66];   // [ci_l][hw], stride 66 kills bank conflicts
    const int t   = threadIdx.x;
    const int hw0 = blockIdx.x * 64;
    const int ci0 = blockIdx.y * 32;
    const int nb  = blockIdx.z;
    const int lhw = t & 63;
    const int cq  = t >> 6;    // 0..3
#pragma unroll
    for (int p = 0; p < 8; ++p) {
        int ci_l = cq + p * 4;
        float v = x[((size_t)(nb * C_CH + ci0 + ci_l)) * HW + hw0 + lhw];
        tile[ci_l * 66 + lhw] = (short)sign_i8(v);
    }
    __syncthreads();
    const int hwi = t >> 2;    // 0..63
    const int ch  = t & 3;     // 8 ci each
    const int hw  = hw0 + hwi;
    const int h   = hw / 56, w_ = hw - h * 56;
    char8 pk;
#pragma unroll
    for (int i = 0; i < 8; ++i) pk[i] = (char)tile[(ch * 8 + i) * 66 + hwi];
    size_t dst = ((size_t)((nb * HP + h + 1) * HP + (w_ + 1))) * C_CH + ci0 + ch * 8;
    *(char8*)(xpad + dst) = pk;   // 8B aligned contiguous
}

// --- implicit-GEMM conv (i8 MFMA): y[co][nsp]; fused channel sum/sumsq
// Round-3 structure (post-mortem of r2 regression):
//   * A back in LDS via gl16 (r2's per-lane global A loads added an L2
//     latency chain + 2x A traffic at ~1.5 blocks/CU TLP — regressed).
//   * NO sched_barrier(0) (m141 failure mode: defeats compiler scheduling).
//     Only zero-cost `asm ""::: "memory"` fences pin loads below barriers.
//   * T4 counted vmcnt with 3-deep LDS rotation:
//       step kb: STAGE(kb+2) -> buf[(kb+2)%3]; vmcnt(8) (= tiles kb+1,kb+2
//       in flight, tile kb guaranteed landed); barrier; ds_read buf[kb%3];
//       16 MFMA; barrier.
//     No vmcnt(0) drain in the main loop. Race-freedom: buffer overwritten
//     at step kb was last ds_read at step kb-1; those reads completed
//     before kb-1's MFMAs (data dep) which completed before barrier #2 of
//     step kb-1 — two barriers of separation.
//   * T2 swizzle retained (both sides; conflicts measured 0).
__global__ __launch_bounds__(256) void k_conv(const char* __restrict__ xpad,
                                              const char* __restrict__ wb,
                                              short* __restrict__ y16,
                                              float* __restrict__ gSum,
                                              float* __restrict__ gSqs) {
    __shared__ char lA[3][8192];     // [buf][co_row 0..127][k 0..63] swizzled chunks
    __shared__ char lB[3][8192];     // [buf][n_row  0..127][k 0..63]
    __shared__ float sSum[128], sSqs[128];

    const int t    = threadIdx.x;
    const int wave = t >> 6, lane = t & 63;
    const int quad = lane >> 4, l16 = lane & 15;
    const int wm   = wave & 1, wn = wave >> 1;
    const int n0   = blockIdx.x * 128;
    const int co0  = blockIdx.y * 128;

    if (t < 128) { sSum[t] = 0.f; sSqs[t] = 0.f; }

    // staging addresses (lane -> 16 rows x 4 chunks of 16B), T2 pre-swizzled source
    const int lr  = lane >> 2;              // row within 16-row chunk
    const int lc  = lane & 3;               // 16B chunk within 64B row
    const int lcs = lc ^ ((lr >> 1) & 3);   // pre-swizzled source chunk
    const uint32_t aOff0 = (uint32_t)(co0 + wave * 32 + lr) * KTOT + lcs * 16;
    const uint32_t aOff1 = aOff0 + 16 * KTOT;
    int nsp0 = n0 + wave * 32 + lr;
    int nb0 = nsp0 / HW; int hwr0 = nsp0 - nb0 * HW; int h0 = hwr0 / 56; int w0 = hwr0 - h0 * 56;
    const uint32_t bOff0 = (uint32_t)((nb0 * HP + h0) * HP + w0) * C_CH + lcs * 16;
    int nsp1 = nsp0 + 16;
    int nb1 = nsp1 / HW; int hwr1 = nsp1 - nb1 * HW; int h1 = hwr1 / 56; int w1 = hwr1 - h1 * 56;
    const uint32_t bOff1 = (uint32_t)((nb1 * HP + h1) * HP + w1) * C_CH + lcs * 16;

    // read-side swizzled chunk offset (constant per lane)
    const int rds = (quad ^ ((l16 >> 1) & 3)) * 16;

    int4v acc[4][4];
#pragma unroll
    for (int i = 0; i < 4; ++i)
#pragma unroll
        for (int j = 0; j < 4; ++j) acc[i][j] = (int4v){0, 0, 0, 0};

#define STAGE(kb_, SB) do {                                                 \
        const int k0_   = (kb_) * 64;                                       \
        const int koff_ = (kb_) >> 2;               /* (kh,kw) index 0..8 */\
        const int ci0_  = ((kb_) & 3) * 64;                                 \
        const int kh_   = koff_ / 3;                                        \
        const int kw_   = koff_ - kh_ * 3;                                  \
        const uint32_t bAdd_ = (uint32_t)(kh_ * HP + kw_) * C_CH + ci0_;    \
        gl16(wb + aOff0 + k0_,     &lA[SB][wave * 2048]);                   \
        gl16(wb + aOff1 + k0_,     &lA[SB][wave * 2048 + 1024]);            \
        gl16(xpad + bOff0 + bAdd_, &lB[SB][wave * 2048]);                   \
        gl16(xpad + bOff1 + bAdd_, &lB[SB][wave * 2048 + 1024]);            \
    } while (0)

#define COMPUTE(RB) do {                                                    \
        int4v af0 = *(const int4v*)&lA[RB][(wm * 64 +  0 + l16) * 64 + rds];\
        int4v af1 = *(const int4v*)&lA[RB][(wm * 64 + 16 + l16) * 64 + rds];\
        int4v af2 = *(const int4v*)&lA[RB][(wm * 64 + 32 + l16) * 64 + rds];\
        int4v af3 = *(const int4v*)&lA[RB][(wm * 64 + 48 + l16) * 64 + rds];\
        int4v bf0 = *(const int4v*)&lB[RB][(wn * 64 +  0 + l16) * 64 + rds];\
        int4v bf1 = *(const int4v*)&lB[RB][(wn * 64 + 16 + l16) * 64 + rds];\
        int4v bf2 = *(const int4v*)&lB[RB][(wn * 64 + 32 + l16) * 64 + rds];\
        int4v bf3 = *(const int4v*)&lB[RB][(wn * 64 + 48 + l16) * 64 + rds];\
        __builtin_amdgcn_s_setprio(1);                                      \
        acc[0][0] = __builtin_amdgcn_mfma_i32_16x16x64_i8(af0, bf0, acc[0][0], 0, 0, 0); \
        acc[0][1] = __builtin_amdgcn_mfma_i32_16x16x64_i8(af0, bf1, acc[0][1], 0, 0, 0); \
        acc[0][2] = __builtin_amdgcn_mfma_i32_16x16x64_i8(af0, bf2, acc[0][2], 0, 0, 0); \
        acc[0][3] = __builtin_amdgcn_mfma_i32_16x16x64_i8(af0, bf3, acc[0][3], 0, 0, 0); \
        acc[1][0] = __builtin_amdgcn_mfma_i32_16x16x64_i8(af1, bf0, acc[1][0], 0, 0, 0); \
        acc[1][1] = __builtin_amdgcn_mfma_i32_16x16x64_i8(af1, bf1, acc[1][1], 0, 0, 0); \
        acc[1][2] = __builtin_amdgcn_mfma_i32_16x16x64_i8(af1, bf2, acc[1][2], 0, 0, 0); \
        acc[1][3] = __builtin_amdgcn_mfma_i32_16x16x64_i8(af1, bf3, acc[1][3], 0, 0, 0); \
        acc[2][0] = __builtin_amdgcn_mfma_i32_16x16x64_i8(af2, bf0, acc[2][0], 0, 0, 0); \
        acc[2][1] = __builtin_amdgcn_mfma_i32_16x16x64_i8(af2, bf1, acc[2][1], 0, 0, 0); \
        acc[2][2] = __builtin_amdgcn_mfma_i32_16x16x64_i8(af2, bf2, acc[2][2], 0, 0, 0); \
        acc[2][3] = __builtin_amdgcn_mfma_i32_16x16x64_i8(af2, bf3, acc[2][3], 0, 0, 0); \
        acc[3][0] = __builtin_amdgcn_mfma_i32_16x16x64_i8(af3, bf0, acc[3][0], 0, 0, 0); \
        acc[3][1] = __builtin_amdgcn_mfma_i32_16x16x64_i8(af3, bf1, acc[3][1], 0, 0, 0); \
        acc[3][2] = __builtin_amdgcn_mfma_i32_16x16x64_i8(af3, bf2, acc[3][2], 0, 0, 0); \
        acc[3][3] = __builtin_amdgcn_mfma_i32_16x16x64_i8(af3, bf3, acc[3][3], 0, 0, 0); \
        __builtin_amdgcn_s_setprio(0);                                      \
    } while (0)

// steady-state step: stage tile kb+2, counted wait for tile kb, compute it
#define SUBS(kb_, RB, SB) do {                                              \
        STAGE((kb_) + 2, SB);                                               \
        asm volatile("s_waitcnt vmcnt(8)" ::: "memory");                    \
        __builtin_amdgcn_s_barrier();                                       \
        asm volatile("" ::: "memory");  /* keep ds_reads below barrier */   \
        COMPUTE(RB);                                                        \
        __builtin_amdgcn_s_barrier();                                       \
    } while (0)

    // prologue: tiles 0 and 1 in flight
    STAGE(0, 0);
    STAGE(1, 1);

    // main loop: kb = 0..32 (stages tiles 2..34), buffer rotation 0,1,2
    for (int kbb = 0; kbb < 33; kbb += 3) {
        SUBS(kbb + 0, 0, 2);
        SUBS(kbb + 1, 1, 0);
        SUBS(kbb + 2, 2, 1);
    }
    // peeled tail: kb=33 stages tile 35; kb=34/35 only drain what's left
    STAGE(35, 2);
    asm volatile("s_waitcnt vmcnt(8)" ::: "memory");
    __builtin_amdgcn_s_barrier();
    asm volatile("" ::: "memory");
    COMPUTE(0);                                   // kb=33
    __builtin_amdgcn_s_barrier();
    asm volatile("s_waitcnt vmcnt(4)" ::: "memory");
    __builtin_amdgcn_s_barrier();
    asm volatile("" ::: "memory");
    COMPUTE(1);                                   // kb=34
    __builtin_amdgcn_s_barrier();
    asm volatile("s_waitcnt vmcnt(0)" ::: "memory");
    __builtin_amdgcn_s_barrier();
    asm volatile("" ::: "memory");
    COMPUTE(2);                                   // kb=35
#undef SUBS
#undef COMPUTE
#undef STAGE

    // epilogue: y16 store + per-channel partial sums
#pragma unroll
    for (int mi = 0; mi < 4; ++mi) {
#pragma unroll
        for (int r = 0; r < 4; ++r) {
            int m = co0 + wm * 64 + mi * 16 + quad * 4 + r;
            float s = 0.f, sq = 0.f;
#pragma unroll
            for (int ni = 0; ni < 4; ++ni) {
                int yi = acc[mi][ni][r];      // exact integer
                float f = (float)yi;
                int n = n0 + wn * 64 + ni * 16 + l16;
                y16[(uint32_t)m * NSP + n] = (short)yi;
                s += f; sq += f * f;
            }
#pragma unroll
            for (int off = 1; off < 16; off <<= 1) {
                s  += __shfl_xor(s, off);
                sq += __shfl_xor(sq, off);
            }
            if (l16 == 0) {
                atomicAdd(&sSum[m - co0], s);
                atomicAdd(&sSqs[m - co0], sq);
            }
        }
    }
    __syncthreads();
    if (t < 128) {
        atomicAdd(&gSum[co0 + t], sSum[t]);
        atomicAdd(&gSqs[co0 + t], sSqs[t]);
    }
}

// --- fused BN stats + apply + residual
__global__ __launch_bounds__(256) void k_out(const short* __restrict__ y16,
                                             const float* __restrict__ x,
                                             const float* __restrict__ gSum,
                                             const float* __restrict__ gSqs,
                                             const float* __restrict__ gamma,
                                             const float* __restrict__ beta,
                                             float* __restrict__ out) {
    int g = blockIdx.x * 256 + threadIdx.x;       // NSP*C_CH/4 threads
    int hw4 = g % 784;
    int tmp = g / 784;
    int co  = tmp & 255;
    int nb  = tmp >> 8;
    const float inv = 1.0f / (float)NSP;
    float mean = gSum[co] * inv;
    float var  = gSqs[co] * inv - mean * mean;
    float a = gamma[co] * rsqrtf(var + 1e-5f);
    float b = beta[co] - mean * a;
    s16x4 yv = *(const s16x4*)&y16[(uint32_t)co * NSP + nb * HW + hw4 * 4];
    size_t xi = ((size_t)(nb * C_CH + co)) * HW + hw4 * 4;
    f32x4v xv = *(const f32x4v*)&x[xi];
    f32x4v o;
#pragma unroll
    for (int i = 0; i < 4; ++i) o[i] = a * (float)yv[i] + b + xv[i];
    *(f32x4v*)&out[xi] = o;
}

extern "C" void kernel_launch(void* const* d_in, const int* in_sizes, int n_in,
                              void* d_out, int out_size, void* d_ws, size_t ws_size,
                              hipStream_t stream) {
    const float* x     = (const float*)d_in[0];
    const float* w     = (const float*)d_in[1];
    const float* gamma = (const float*)d_in[2];
    const float* beta  = (const float*)d_in[3];
    float* out = (float*)d_out;
    char* ws = (char*)d_ws;

    char*  xpad = ws;
    char*  wbp  = ws + WB_OFF_B;
    short* y16  = (short*)(ws + Y_OFF_B);
    float* gSum = (float*)(ws + STAT_OFF_B);
    float* gSqs = gSum + 256;

    hipMemsetAsync(xpad, 0, XPAD_BYTES, stream);                 // padding zeros

    k_binw<<<(int)((WB_BYTES + 255) / 256), 256, 0, stream>>>(w, wbp, gSum);
    k_binx<<<dim3(49, 8, 32), 256, 0, stream>>>(x, xpad);
    k_conv<<<dim3(NSP / 128, 2), 256, 0, stream>>>(xpad, wbp, y16, gSum, gSqs);
    k_out<<<(NSP * C_CH / 4) / 256, 256, 0, stream>>>(y16, x, gSum, gSqs, gamma, beta, out);
}

// Round 4
// 339.332 us; speedup vs baseline: 1.1228x; 1.0201x over previous
//
#include <hip/hip_runtime.h>
#include <stdint.h>
#include <stddef.h>

// Problem constants
#define N_B   32
#define C_CH  256
#define H_S   56
#define W_S   56
#define HW    (H_S*W_S)        // 3136
#define NSP   (N_B*HW)         // 100352
#define KTOT  (C_CH*9)         // 2304 (bytes per row in i8)
#define HP    58               // padded spatial

// Workspace layout (bytes) — all i8
#define XPAD_BYTES ((size_t)N_B*HP*HP*C_CH)        // 27,557,888
#define WB_OFF_B   XPAD_BYTES
#define WB_BYTES   ((size_t)C_CH*KTOT)             // 589,824
#define Y_OFF_B    (WB_OFF_B + WB_BYTES)
#define STAT_OFF_B (Y_OFF_B + (size_t)C_CH*NSP*2)

typedef int    int4v  __attribute__((ext_vector_type(4)));
typedef short  s16x4  __attribute__((ext_vector_type(4)));
typedef short  s16x8  __attribute__((ext_vector_type(8)));
typedef char   char8  __attribute__((ext_vector_type(8)));
typedef float  f32x4v __attribute__((ext_vector_type(4)));

__device__ __forceinline__ void gl16(const void* g, void* l) {
    __builtin_amdgcn_global_load_lds((const __attribute__((address_space(1))) void*)g,
                                     (__attribute__((address_space(3))) void*)l, 16, 0, 0);
}

__device__ __forceinline__ char sign_i8(float v) {
    return v > 0.f ? (char)1 : (v < 0.f ? (char)-1 : (char)0);
}

// --- binarize weights (i8), reorder K; also zero the stat accumulators
__global__ __launch_bounds__(256) void k_binw(const float* __restrict__ w,
                                              char* __restrict__ wb,
                                              float* __restrict__ gStat) {
    int g = blockIdx.x * 256 + threadIdx.x;
    if (blockIdx.x == 0 && threadIdx.x < 512) gStat[threadIdx.x] = 0.f;
    if (g >= (int)WB_BYTES) return;
    int co = g / KTOT;
    int r  = g - co * KTOT;
    int ci = r / 9;
    int koff = r - ci * 9;
    wb[co * KTOT + koff * C_CH + ci] = sign_i8(w[g]);
}

// --- binarize x into zero-padded [nb][h+1][w+1][ci] i8 via LDS transpose
// Round-4: float4-vectorized global reads (4x fewer VMEM instrs, G13);
// LDS stride 68 shorts so packed s16x4 stores are 8B-aligned.
__global__ __launch_bounds__(256) void k_binx(const float* __restrict__ x,
                                              char* __restrict__ xpad) {
    __shared__ short tile[32 * 68];   // [ci_l][hw], stride 68 (8B-aligned rows)
    const int t     = threadIdx.x;
    const int hw0   = blockIdx.x * 64;
    const int ci0   = blockIdx.y * 32;
    const int nb    = blockIdx.z;
    const int chunk = t & 15;          // 16 chunks x 4 floats = 64 hw
    const int cih   = t >> 4;          // 0..15
#pragma unroll
    for (int p = 0; p < 2; ++p) {
        int ci_l = cih + p * 16;
        f32x4v v = *(const f32x4v*)&x[((size_t)(nb * C_CH + ci0 + ci_l)) * HW + hw0 + chunk * 4];
        s16x4 pk;
#pragma unroll
        for (int j = 0; j < 4; ++j) pk[j] = (short)sign_i8(v[j]);
        *(s16x4*)&tile[ci_l * 68 + chunk * 4] = pk;
    }
    __syncthreads();
    const int hwi = t >> 2;    // 0..63
    const int ch  = t & 3;     // 8 ci each
    const int hw  = hw0 + hwi;
    const int h   = hw / 56, w_ = hw - h * 56;
    char8 pk;
#pragma unroll
    for (int i = 0; i < 8; ++i) pk[i] = (char)tile[(ch * 8 + i) * 68 + hwi];
    size_t dst = ((size_t)((nb * HP + h + 1) * HP + (w_ + 1))) * C_CH + ci0 + ch * 8;
    *(char8*)(xpad + dst) = pk;   // 8B aligned contiguous
}

// --- implicit-GEMM conv (i8 MFMA): y[co][nsp]; fused channel sum/sumsq
// Round-4: REVERT to the round-0 structure (best measured: 128us; all three
// deep-pipeline variants regressed — T4/T5 are gated on the 8-phase/8-wave
// structure we don't have). Single change kept from r1: T2 XOR-swizzle on
// both sides (counter-verified: SQ_LDS_BANK_CONFLICT 7.2M -> 0).
__global__ __launch_bounds__(256) void k_conv(const char* __restrict__ xpad,
                                              const char* __restrict__ wb,
                                              short* __restrict__ y16,
                                              float* __restrict__ gSum,
                                              float* __restrict__ gSqs) {
    __shared__ char lA[128 * 64];   // [co_row][k] 64B rows (BK=64 i8)
    __shared__ char lB[128 * 64];   // [n_row][k]
    __shared__ float sSum[128], sSqs[128];

    const int t    = threadIdx.x;
    const int wave = t >> 6, lane = t & 63;
    const int quad = lane >> 4, l16 = lane & 15;
    const int wm   = wave & 1, wn = wave >> 1;
    const int n0   = blockIdx.x * 128;
    const int co0  = blockIdx.y * 128;

    if (t < 128) { sSum[t] = 0.f; sSqs[t] = 0.f; }

    // staging addresses (lane -> 16 rows x 4 chunks of 16B), T2 pre-swizzled source
    const int lr  = lane >> 2;              // row within 16-row chunk
    const int lc  = lane & 3;               // 16B chunk within 64B row
    const int lcs = lc ^ ((lr >> 1) & 3);   // pre-swizzled source chunk
    const uint32_t aOff0 = (uint32_t)(co0 + wave * 32 + lr) * KTOT + lcs * 16;
    const uint32_t aOff1 = aOff0 + 16 * KTOT;
    int nsp0 = n0 + wave * 32 + lr;
    int nb0 = nsp0 / HW; int hwr0 = nsp0 - nb0 * HW; int h0 = hwr0 / 56; int w0 = hwr0 - h0 * 56;
    const uint32_t bOff0 = (uint32_t)((nb0 * HP + h0) * HP + w0) * C_CH + lcs * 16;
    int nsp1 = nsp0 + 16;
    int nb1 = nsp1 / HW; int hwr1 = nsp1 - nb1 * HW; int h1 = hwr1 / 56; int w1 = hwr1 - h1 * 56;
    const uint32_t bOff1 = (uint32_t)((nb1 * HP + h1) * HP + w1) * C_CH + lcs * 16;

    // read-side swizzled chunk offset (constant per lane)
    const int rds = (quad ^ ((l16 >> 1) & 3)) * 16;

    int4v acc[4][4];
#pragma unroll
    for (int i = 0; i < 4; ++i)
#pragma unroll
        for (int j = 0; j < 4; ++j) acc[i][j] = (int4v){0, 0, 0, 0};

    for (int kb = 0; kb < KTOT / 64; ++kb) {              // 36 iterations
        const int k0   = kb * 64;
        const int koff = kb >> 2;              // (kh,kw) index 0..8
        const int ci0_ = (kb & 3) * 64;
        const int kh   = koff / 3;
        const int kw   = koff - kh * 3;
        const uint32_t bAdd = (uint32_t)(kh * HP + kw) * C_CH + ci0_;   // wave-uniform
        __syncthreads();
        gl16(wb + aOff0 + k0,     &lA[wave * 2048]);
        gl16(wb + aOff1 + k0,     &lA[wave * 2048 + 1024]);
        gl16(xpad + bOff0 + bAdd, &lB[wave * 2048]);
        gl16(xpad + bOff1 + bAdd, &lB[wave * 2048 + 1024]);
        __syncthreads();
        int4v af[4], bf[4];
#pragma unroll
        for (int i = 0; i < 4; ++i)
            af[i] = *(const int4v*)&lA[(wm * 64 + i * 16 + l16) * 64 + rds];
#pragma unroll
        for (int i = 0; i < 4; ++i)
            bf[i] = *(const int4v*)&lB[(wn * 64 + i * 16 + l16) * 64 + rds];
#pragma unroll
        for (int mi = 0; mi < 4; ++mi)
#pragma unroll
            for (int ni = 0; ni < 4; ++ni)
                acc[mi][ni] = __builtin_amdgcn_mfma_i32_16x16x64_i8(af[mi], bf[ni], acc[mi][ni], 0, 0, 0);
    }

    // epilogue: y16 store + per-channel partial sums
#pragma unroll
    for (int mi = 0; mi < 4; ++mi) {
#pragma unroll
        for (int r = 0; r < 4; ++r) {
            int m = co0 + wm * 64 + mi * 16 + quad * 4 + r;
            float s = 0.f, sq = 0.f;
#pragma unroll
            for (int ni = 0; ni < 4; ++ni) {
                int yi = acc[mi][ni][r];      // exact integer
                float f = (float)yi;
                int n = n0 + wn * 64 + ni * 16 + l16;
                y16[(uint32_t)m * NSP + n] = (short)yi;
                s += f; sq += f * f;
            }
#pragma unroll
            for (int off = 1; off < 16; off <<= 1) {
                s  += __shfl_xor(s, off);
                sq += __shfl_xor(sq, off);
            }
            if (l16 == 0) {
                atomicAdd(&sSum[m - co0], s);
                atomicAdd(&sSqs[m - co0], sq);
            }
        }
    }
    __syncthreads();
    if (t < 128) {
        atomicAdd(&gSum[co0 + t], sSum[t]);
        atomicAdd(&gSqs[co0 + t], sSqs[t]);
    }
}

// --- fused BN stats + apply + residual
// Round-4: 8 elems/thread (halved thread count, 2x ILP on loads) +
// nontemporal stores for `out` (write-once stream; keep L2/L3 for y16/x reuse).
__global__ __launch_bounds__(256) void k_out(const short* __restrict__ y16,
                                             const float* __restrict__ x,
                                             const float* __restrict__ gSum,
                                             const float* __restrict__ gSqs,
                                             const float* __restrict__ gamma,
                                             const float* __restrict__ beta,
                                             float* __restrict__ out) {
    int g = blockIdx.x * 256 + threadIdx.x;       // NSP*C_CH/8 threads
    int hw8 = g % 392;                            // 3136/8
    int tmp = g / 392;
    int co  = tmp & 255;
    int nb  = tmp >> 8;
    const float inv = 1.0f / (float)NSP;
    float mean = gSum[co] * inv;
    float var  = gSqs[co] * inv - mean * mean;
    float a = gamma[co] * rsqrtf(var + 1e-5f);
    float b = beta[co] - mean * a;
    s16x8 yv = *(const s16x8*)&y16[(uint32_t)co * NSP + nb * HW + hw8 * 8];
    size_t xi = ((size_t)(nb * C_CH + co)) * HW + hw8 * 8;
    f32x4v xv0 = *(const f32x4v*)&x[xi];
    f32x4v xv1 = *(const f32x4v*)&x[xi + 4];
    f32x4v o0, o1;
#pragma unroll
    for (int i = 0; i < 4; ++i) {
        o0[i] = a * (float)yv[i]     + b + xv0[i];
        o1[i] = a * (float)yv[4 + i] + b + xv1[i];
    }
    __builtin_nontemporal_store(o0, (f32x4v*)&out[xi]);
    __builtin_nontemporal_store(o1, (f32x4v*)&out[xi + 4]);
}

extern "C" void kernel_launch(void* const* d_in, const int* in_sizes, int n_in,
                              void* d_out, int out_size, void* d_ws, size_t ws_size,
                              hipStream_t stream) {
    const float* x     = (const float*)d_in[0];
    const float* w     = (const float*)d_in[1];
    const float* gamma = (const float*)d_in[2];
    const float* beta  = (const float*)d_in[3];
    float* out = (float*)d_out;
    char* ws = (char*)d_ws;

    char*  xpad = ws;
    char*  wbp  = ws + WB_OFF_B;
    short* y16  = (short*)(ws + Y_OFF_B);
    float* gSum = (float*)(ws + STAT_OFF_B);
    float* gSqs = gSum + 256;

    hipMemsetAsync(xpad, 0, XPAD_BYTES, stream);                 // padding zeros

    k_binw<<<(int)((WB_BYTES + 255) / 256), 256, 0, stream>>>(w, wbp, gSum);
    k_binx<<<dim3(49, 8, 32), 256, 0, stream>>>(x, xpad);
    k_conv<<<dim3(NSP / 128, 2), 256, 0, stream>>>(xpad, wbp, y16, gSum, gSqs);
    k_out<<<(NSP * C_CH / 8) / 256, 256, 0, stream>>>(y16, x, gSum, gSqs, gamma, beta, out);
}

// Round 5
// 324.875 us; speedup vs baseline: 1.1728x; 1.0445x over previous
//
#include <hip/hip_runtime.h>
#include <stdint.h>
#include <stddef.h>

// Problem constants
#define N_B   32
#define C_CH  256
#define H_S   56
#define W_S   56
#define HW    (H_S*W_S)        // 3136
#define NSP   (N_B*HW)         // 100352
#define KTOT  (C_CH*9)         // 2304 (bytes per row in i8)
#define HP    58               // padded spatial

// Workspace layout (bytes) — all i8
#define XPAD_BYTES ((size_t)N_B*HP*HP*C_CH)        // 27,557,888
#define WB_OFF_B   XPAD_BYTES
#define WB_BYTES   ((size_t)C_CH*KTOT)             // 589,824
#define Y_OFF_B    (WB_OFF_B + WB_BYTES)
#define STAT_OFF_B (Y_OFF_B + (size_t)C_CH*NSP*2)

typedef int    int4v  __attribute__((ext_vector_type(4)));
typedef short  s16x4  __attribute__((ext_vector_type(4)));
typedef short  s16x8  __attribute__((ext_vector_type(8)));
typedef char   char8  __attribute__((ext_vector_type(8)));
typedef float  f32x4v __attribute__((ext_vector_type(4)));

__device__ __forceinline__ void gl16(const void* g, void* l) {
    __builtin_amdgcn_global_load_lds((const __attribute__((address_space(1))) void*)g,
                                     (__attribute__((address_space(3))) void*)l, 16, 0, 0);
}

__device__ __forceinline__ char sign_i8(float v) {
    return v > 0.f ? (char)1 : (v < 0.f ? (char)-1 : (char)0);
}

// --- fused pre-pass: binarize x (interior), write xpad padding zeros
//     (replaces hipMemsetAsync), binarize+reorder weights, zero stats.
// grid (54, 8, 32): x=0..48 interior binx; x=49..52 border zeros; x=53 binw.
__global__ __launch_bounds__(256) void k_pre(const float* __restrict__ x,
                                             const float* __restrict__ w,
                                             char* __restrict__ xpad,
                                             char* __restrict__ wb,
                                             float* __restrict__ gStat) {
    const int t  = threadIdx.x;
    const int bx = blockIdx.x;
    const int nb  = blockIdx.z;
    const int ci0 = blockIdx.y * 32;

    if (bx < 49) {
        // ---- interior binarize + NCHW -> [nb][h+1][w+1][ci] transpose
        __shared__ short tile[32 * 68];   // stride 68 shorts (8B-aligned rows)
        const int hw0   = bx * 64;
        const int chunk = t & 15;          // 16 chunks x 4 floats = 64 hw
        const int cih   = t >> 4;          // 0..15
#pragma unroll
        for (int p = 0; p < 2; ++p) {
            int ci_l = cih + p * 16;
            f32x4v v = *(const f32x4v*)&x[((size_t)(nb * C_CH + ci0 + ci_l)) * HW + hw0 + chunk * 4];
            s16x4 pk;
#pragma unroll
            for (int j = 0; j < 4; ++j) pk[j] = (short)sign_i8(v[j]);
            *(s16x4*)&tile[ci_l * 68 + chunk * 4] = pk;
        }
        __syncthreads();
        const int hwi = t >> 2;    // 0..63
        const int ch  = t & 3;     // 8 ci each
        const int hw  = hw0 + hwi;
        const int h   = hw / 56, w_ = hw - h * 56;
        char8 pk;
#pragma unroll
        for (int i = 0; i < 8; ++i) pk[i] = (char)tile[(ch * 8 + i) * 68 + hwi];
        size_t dst = ((size_t)((nb * HP + h + 1) * HP + (w_ + 1))) * C_CH + ci0 + ch * 8;
        *(char8*)(xpad + dst) = pk;   // 8B aligned contiguous
    } else if (bx < 53) {
        // ---- border zeros: 228 border cells of [58][58], 32 ci per block-y
        int idx = (bx - 49) * 256 + t;      // 0..1023; need 228*4 = 912
        if (idx < 912) {
            int pos = idx >> 2, sub = idx & 3;
            int h, w_;
            if (pos < 58)       { h = 0;         w_ = pos; }
            else if (pos < 116) { h = 57;        w_ = pos - 58; }
            else if (pos < 172) { h = pos - 115; w_ = 0; }
            else                { h = pos - 171; w_ = 57; }
            size_t dst = ((size_t)((nb * HP + h) * HP + w_)) * C_CH + ci0 + sub * 8;
            *(char8*)(xpad + dst) = (char8){0, 0, 0, 0, 0, 0, 0, 0};
        }
    } else {
        // ---- binarize weights, reorder K: wb[co][koff][ci]
        if (blockIdx.y == 0 && blockIdx.z == 0 && t < 512) gStat[t] = 0.f;
        int gid = (blockIdx.z * 8 + blockIdx.y) * 256 + t;    // 0..65535
#pragma unroll
        for (int i = 0; i < 9; ++i) {
            int g = gid + i * 65536;                          // 9*65536 == WB_BYTES
            int co = g / KTOT;
            int r  = g - co * KTOT;
            int ci = r / 9;
            int koff = r - ci * 9;
            wb[co * KTOT + koff * C_CH + ci] = sign_i8(w[g]);
        }
    }
}

// --- implicit-GEMM conv (i8 MFMA): y[co][nsp]; fused channel sum/sumsq
// Round-5: keep the proven 2-barrier structure (r0/r4 best) but double BK
// to 128: 32 MFMAs per barrier-drain instead of 16 — m97-parity staging
// amortization (i8 16x16x64 does K=64/instr, so BK=64 gave only half the
// per-barrier MFMA work of the 37%-MfmaUtil bf16 reference).
// 128B-row swizzle: LDS[row][c] holds global chunk c^(row&7); staged via
// pre-swizzled global source (gl16 dest stays lane-linear, rule #21),
// read back with the same XOR. 2 lanes/bank -> conflict-free.
__global__ __launch_bounds__(256) void k_conv(const char* __restrict__ xpad,
                                              const char* __restrict__ wb,
                                              short* __restrict__ y16,
                                              float* __restrict__ gSum,
                                              float* __restrict__ gSqs) {
    __shared__ char lA[128 * 128];   // [co_row][k 0..127], swizzled chunks
    __shared__ char lB[128 * 128];   // [n_row][k]
    __shared__ float sSum[128], sSqs[128];

    const int t    = threadIdx.x;
    const int wave = t >> 6, lane = t & 63;
    const int quad = lane >> 4, l16 = lane & 15;
    const int wm   = wave & 1, wn = wave >> 1;
    const int n0   = blockIdx.x * 128;
    const int co0  = blockIdx.y * 128;

    if (t < 128) { sSum[t] = 0.f; sSqs[t] = 0.f; }

    // Staging: wave stages rows [wave*32, +32). gl16 j (0..3) fills LDS rows
    // wave*32 + j*8 + (lane>>3), chunk (lane&7). Source chunk pre-swizzled:
    const int swz = (lane & 7) ^ (lane >> 3);   // (chunk) ^ (row & 7)
    uint32_t aOff[4], bOff[4];
#pragma unroll
    for (int j = 0; j < 4; ++j) {
        int row = wave * 32 + j * 8 + (lane >> 3);
        aOff[j] = (uint32_t)(co0 + row) * KTOT + swz * 16;
        int nsp = n0 + row;
        int nb = nsp / HW; int hwr = nsp - nb * HW;
        int h = hwr / 56;  int w_  = hwr - h * 56;
        bOff[j] = (uint32_t)((nb * HP + h) * HP + w_) * C_CH + swz * 16;
    }

    int4v acc[4][4];
#pragma unroll
    for (int i = 0; i < 4; ++i)
#pragma unroll
        for (int j = 0; j < 4; ++j) acc[i][j] = (int4v){0, 0, 0, 0};

    for (int kbb = 0; kbb < 18; ++kbb) {                  // BK=128 steps
        const int koff = kbb >> 1;                        // (kh,kw) 0..8
        const int kh   = koff / 3;
        const int kw   = koff - kh * 3;
        const uint32_t bAdd = (uint32_t)(kh * HP + kw) * C_CH + (kbb & 1) * 128;
        const uint32_t aAdd = (uint32_t)kbb * 128;
        __syncthreads();
#pragma unroll
        for (int j = 0; j < 4; ++j) gl16(wb   + aOff[j] + aAdd, &lA[wave * 4096 + j * 1024]);
#pragma unroll
        for (int j = 0; j < 4; ++j) gl16(xpad + bOff[j] + bAdd, &lB[wave * 4096 + j * 1024]);
        __syncthreads();
        int4v af[2][4], bf[2][4];
#pragma unroll
        for (int ks = 0; ks < 2; ++ks) {
#pragma unroll
            for (int i = 0; i < 4; ++i) {
                const int ar = wm * 64 + i * 16 + l16;
                const int br = wn * 64 + i * 16 + l16;
                const int cs = ((quad + ks * 4) ^ (l16 & 7)) * 16;
                af[ks][i] = *(const int4v*)&lA[ar * 128 + cs];
                bf[ks][i] = *(const int4v*)&lB[br * 128 + cs];
            }
        }
#pragma unroll
        for (int ks = 0; ks < 2; ++ks)
#pragma unroll
            for (int mi = 0; mi < 4; ++mi)
#pragma unroll
                for (int ni = 0; ni < 4; ++ni)
                    acc[mi][ni] = __builtin_amdgcn_mfma_i32_16x16x64_i8(af[ks][mi], bf[ks][ni], acc[mi][ni], 0, 0, 0);
    }

    // epilogue: y16 store + per-channel partial sums
#pragma unroll
    for (int mi = 0; mi < 4; ++mi) {
#pragma unroll
        for (int r = 0; r < 4; ++r) {
            int m = co0 + wm * 64 + mi * 16 + quad * 4 + r;
            float s = 0.f, sq = 0.f;
#pragma unroll
            for (int ni = 0; ni < 4; ++ni) {
                int yi = acc[mi][ni][r];      // exact integer
                float f = (float)yi;
                int n = n0 + wn * 64 + ni * 16 + l16;
                y16[(uint32_t)m * NSP + n] = (short)yi;
                s += f; sq += f * f;
            }
#pragma unroll
            for (int off = 1; off < 16; off <<= 1) {
                s  += __shfl_xor(s, off);
                sq += __shfl_xor(sq, off);
            }
            if (l16 == 0) {
                atomicAdd(&sSum[m - co0], s);
                atomicAdd(&sSqs[m - co0], sq);
            }
        }
    }
    __syncthreads();
    if (t < 128) {
        atomicAdd(&gSum[co0 + t], sSum[t]);
        atomicAdd(&gSqs[co0 + t], sSqs[t]);
    }
}

// --- fused BN stats + apply + residual (8 elems/thread, NT stores for out)
__global__ __launch_bounds__(256) void k_out(const short* __restrict__ y16,
                                             const float* __restrict__ x,
                                             const float* __restrict__ gSum,
                                             const float* __restrict__ gSqs,
                                             const float* __restrict__ gamma,
                                             const float* __restrict__ beta,
                                             float* __restrict__ out) {
    int g = blockIdx.x * 256 + threadIdx.x;       // NSP*C_CH/8 threads
    int hw8 = g % 392;                            // 3136/8
    int tmp = g / 392;
    int co  = tmp & 255;
    int nb  = tmp >> 8;
    const float inv = 1.0f / (float)NSP;
    float mean = gSum[co] * inv;
    float var  = gSqs[co] * inv - mean * mean;
    float a = gamma[co] * rsqrtf(var + 1e-5f);
    float b = beta[co] - mean * a;
    s16x8 yv = *(const s16x8*)&y16[(uint32_t)co * NSP + nb * HW + hw8 * 8];
    size_t xi = ((size_t)(nb * C_CH + co)) * HW + hw8 * 8;
    f32x4v xv0 = *(const f32x4v*)&x[xi];
    f32x4v xv1 = *(const f32x4v*)&x[xi + 4];
    f32x4v o0, o1;
#pragma unroll
    for (int i = 0; i < 4; ++i) {
        o0[i] = a * (float)yv[i]     + b + xv0[i];
        o1[i] = a * (float)yv[4 + i] + b + xv1[i];
    }
    __builtin_nontemporal_store(o0, (f32x4v*)&out[xi]);
    __builtin_nontemporal_store(o1, (f32x4v*)&out[xi + 4]);
}

extern "C" void kernel_launch(void* const* d_in, const int* in_sizes, int n_in,
                              void* d_out, int out_size, void* d_ws, size_t ws_size,
                              hipStream_t stream) {
    const float* x     = (const float*)d_in[0];
    const float* w     = (const float*)d_in[1];
    const float* gamma = (const float*)d_in[2];
    const float* beta  = (const float*)d_in[3];
    float* out = (float*)d_out;
    char* ws = (char*)d_ws;

    char*  xpad = ws;
    char*  wbp  = ws + WB_OFF_B;
    short* y16  = (short*)(ws + Y_OFF_B);
    float* gSum = (float*)(ws + STAT_OFF_B);
    float* gSqs = gSum + 256;

    // k_pre covers padding zeros (no memset), weight binarize, stat zeroing
    k_pre<<<dim3(54, 8, 32), 256, 0, stream>>>(x, w, xpad, wbp, gSum);
    k_conv<<<dim3(NSP / 128, 2), 256, 0, stream>>>(xpad, wbp, y16, gSum, gSqs);
    k_out<<<(NSP * C_CH / 8) / 256, 256, 0, stream>>>(y16, x, gSum, gSqs, gamma, beta, out);
}